// Round 3
// baseline (573.122 us; speedup 1.0000x reference)
//
#include <hip/hip_runtime.h>

#define NODE 8192
#define FEAT 64
#define OUTD 64
#define NCOL 256  // BATCH*OUTD

typedef float f32x4 __attribute__((ext_vector_type(4)));
typedef short s16x8 __attribute__((ext_vector_type(8)));
typedef short s16x4 __attribute__((ext_vector_type(4)));
typedef int   i32x4 __attribute__((ext_vector_type(4)));

__device__ __forceinline__ short f2bf(float f) {
    // round-to-nearest-even fp32 -> bf16 (finite inputs)
    unsigned u = __builtin_bit_cast(unsigned, f);
    u += 0x7FFFu + ((u >> 16) & 1u);
    return (short)(u >> 16);
}

__device__ __forceinline__ s16x4 cvt4(const f32x4& v) {
    s16x4 r;
#pragma unroll
    for (int i = 0; i < 4; ++i) r[i] = f2bf(v[i]);
    return r;
}

// ---------------------------------------------------------------------------
// k0: bias2[o] = b_out[o] + sum_f nl_b[f] * w_out[o,f]
// ---------------------------------------------------------------------------
__global__ void bias2_kernel(const float* __restrict__ nl_b,
                             const float* __restrict__ w_out,
                             const float* __restrict__ b_out,
                             float* __restrict__ bias2) {
    __shared__ float part[4][64];
    const int o = threadIdx.x & 63;
    const int fc = threadIdx.x >> 6;
    float s = 0.f;
#pragma unroll
    for (int i = 0; i < 16; ++i) {
        int f = fc * 16 + i;
        s += nl_b[f] * w_out[o * FEAT + f];
    }
    part[fc][o] = s;
    __syncthreads();
    if (fc == 0)
        bias2[o] = b_out[o] + part[0][o] + part[1][o] + part[2][o] + part[3][o];
}

// ---------------------------------------------------------------------------
// k1: Yt[b*64+o][j] = bf16( sum_f W2[o,f] * x[b,j,f] ), W2=w_out*nl_w/sqrt2
// Coalesced float4 LDS staging; pure VALU. (unchanged from round 2)
// ---------------------------------------------------------------------------
__global__ __launch_bounds__(256) void build_yt_kernel(
    const float* __restrict__ x, const float* __restrict__ nl_w,
    const float* __restrict__ w_out, unsigned short* __restrict__ yt) {
    __shared__ float xs[64 * 65];
    __shared__ float w2s[64 * 65];
    const int tid = threadIdx.x;
    const int b   = (int)blockIdx.x >> 7;
    const int j0  = ((int)blockIdx.x & 127) << 6;

    const f32x4* src = (const f32x4*)(x + ((size_t)b * NODE + j0) * FEAT);
#pragma unroll
    for (int i = tid; i < 1024; i += 256) {
        f32x4 v = src[i];
        int j = i >> 4, f = (i & 15) << 2;
        float* d = &xs[j * 65 + f];
        d[0] = v[0]; d[1] = v[1]; d[2] = v[2]; d[3] = v[3];
    }
    for (int i = tid; i < 4096; i += 256) {
        int f = i & 63;
        w2s[(i >> 6) * 65 + f] = w_out[i] * (0.70710678118654752f * nl_w[f]);
    }
    __syncthreads();

    const int j  = tid & 63;
    const int o0 = (tid >> 6) << 4;
    float acc[16];
#pragma unroll
    for (int r = 0; r < 16; ++r) acc[r] = 0.f;
    for (int f = 0; f < 64; ++f) {
        float xv = xs[j * 65 + f];
#pragma unroll
        for (int r = 0; r < 16; ++r) acc[r] += w2s[(o0 + r) * 65 + f] * xv;
    }
#pragma unroll
    for (int r = 0; r < 16; ++r)
        yt[(size_t)(b * OUTD + o0 + r) * NODE + j0 + j] = (unsigned short)f2bf(acc[r]);
}

// ---------------------------------------------------------------------------
// k2: out[b,i,o] = sum_j adj[i,j] * Y[j, b*64+o] + bias2[o]
// Grid 512 blocks (256 row-blocks of 32 x 2 col-halves of 128), 512 threads =
// 8 waves = 2 ks (K-halves, LDS-reduced) x 2 mi (16-row halves) x 2 bi
// (64-col halves). Wave tile 16m x 64n, BK=64 per round, 64 rounds.
//   A: staged fp32->bf16 into LDS, rows padded to 144B (conflict-free b128
//      frag reads), fully-coalesced global loads (8 lanes x 128B per row).
//      2-round prefetch pipeline: load k(r+2) at round r, LDS-write at r+1,
//      consume at r+2 => ~1000cy structural latency cover.
//   B: Yt is 4MB (L2-resident); direct 16B frag loads, 1-round reg prefetch.
// R2 failure mode fixed: VGPR=32/60 showed compiler collapsed reg dbuf; LDS
// pipeline + distinct slot regs make the overlap structural.
// ---------------------------------------------------------------------------
__global__ __launch_bounds__(512, 4) void gemm_adj_kernel(
    const float* __restrict__ adj, const unsigned short* __restrict__ yt,
    const float* __restrict__ bias2, float* __restrict__ out) {
    // As: [ks][buf][32 rows][72 elts] bf16 (144B padded rows) = 18.4KB
    __shared__ __align__(16) unsigned short As[2 * 2 * 32 * 72];
    __shared__ f32x4 scr[4][4][64];  // ks-reduction scratch, 16KB

    const int tid  = threadIdx.x;
    const int lane = tid & 63;
    const int w    = tid >> 6;
    const int bi   = w & 1;
    const int mi   = (w >> 1) & 1;
    const int ks   = w >> 2;            // == tid>>8
    const int t16  = lane & 15;
    const int quad = lane >> 4;
    const int rb   = (int)blockIdx.x >> 1;
    const int cb2  = (int)blockIdx.x & 1;
    const int row0 = rb * 32;
    const int kbeg = ks * 4096;

    // --- staging role (per ks-group of 256 threads) ---
    const int lt   = tid & 255;
    const int srow = lt >> 3;  // 0..31
    const int sc16 = lt & 7;   // 16B chunk within 128B line
    const float* aG = adj + (size_t)(row0 + srow) * NODE + sc16 * 4;
    unsigned short* Aks = As + ks * 4608;
    const int woff = srow * 72 + sc16 * 4;  // elt offset of this thread's 8B write

    // --- B pointers (direct global, L2-hot) ---
    const unsigned short* bp =
        yt + (size_t)(cb2 * 128 + bi * 64 + t16) * NODE + kbeg + quad * 8;

    f32x4 acc[4];
#pragma unroll
    for (int n = 0; n < 4; ++n) acc[n] = (f32x4){0.f, 0.f, 0.f, 0.f};

    i32x4 B[4][2];
    f32x4 aS[2][2];

    // ---- prologue ----
    {
        // round-0 A data straight to buf0
        f32x4 p0 = *(const f32x4*)(aG + kbeg);
        f32x4 p1 = *(const f32x4*)(aG + kbeg + 32);
        *(s16x4*)(Aks + woff)      = cvt4(p0);
        *(s16x4*)(Aks + woff + 32) = cvt4(p1);
        // slot1 <- k+64 (written to buf1 at r=0)
        aS[1][0] = *(const f32x4*)(aG + kbeg + 64);
        aS[1][1] = *(const f32x4*)(aG + kbeg + 96);
        // B for round 0
#pragma unroll
        for (int n = 0; n < 4; ++n)
#pragma unroll
            for (int kf = 0; kf < 2; ++kf)
                B[n][kf] = *(const i32x4*)(bp + (size_t)n * 16 * NODE + kf * 32);
    }
    __syncthreads();

    const int fro = (mi * 16 + t16) * 72 + quad * 8;  // A-frag elt offset (kf=0)
    for (int r = 0; r < 64; ++r) {
        const int cur = r & 1;
        // issue A global loads for k(r+2) into slot cur
        if (r < 62) {
            const int ko = kbeg + (r + 2) * 64;
            aS[cur][0] = *(const f32x4*)(aG + ko);
            aS[cur][1] = *(const f32x4*)(aG + ko + 32);
        }
        // compute round r
        const unsigned short* Ab = Aks + cur * 2304;
        s16x8 af0 = *(const s16x8*)(Ab + fro);
        s16x8 af1 = *(const s16x8*)(Ab + fro + 32);
#pragma unroll
        for (int n = 0; n < 4; ++n) {
            acc[n] = __builtin_amdgcn_mfma_f32_16x16x32_bf16(
                af0, __builtin_bit_cast(s16x8, B[n][0]), acc[n], 0, 0, 0);
            acc[n] = __builtin_amdgcn_mfma_f32_16x16x32_bf16(
                af1, __builtin_bit_cast(s16x8, B[n][1]), acc[n], 0, 0, 0);
        }
        if (r < 63) {
            // B prefetch for round r+1
            const int ko = (r + 1) * 64;
#pragma unroll
            for (int n = 0; n < 4; ++n)
#pragma unroll
                for (int kf = 0; kf < 2; ++kf)
                    B[n][kf] = *(const i32x4*)(bp + (size_t)n * 16 * NODE + ko + kf * 32);
            // cvt + LDS-write A for round r+1 (slot cur^1, loaded at r-1)
            unsigned short* Awb = Aks + (cur ^ 1) * 2304 + woff;
            *(s16x4*)Awb        = cvt4(aS[cur ^ 1][0]);
            *(s16x4*)(Awb + 32) = cvt4(aS[cur ^ 1][1]);
        }
        __syncthreads();
    }

    // ---- ks reduction + epilogue ----
    const int tI = bi * 2 + mi;
    if (ks == 1) {
#pragma unroll
        for (int n = 0; n < 4; ++n) scr[tI][n][lane] = acc[n];
    }
    __syncthreads();
    if (ks == 0) {
        const int b  = cb2 * 2 + bi;
        const int i0 = row0 + mi * 16 + quad * 4;
#pragma unroll
        for (int n = 0; n < 4; ++n) {
            f32x4 other = scr[tI][n][lane];
            const float bv = bias2[n * 16 + t16];
            float* op = out + ((size_t)b * NODE + i0) * OUTD + n * 16 + t16;
#pragma unroll
            for (int rr = 0; rr < 4; ++rr)
                op[(size_t)rr * OUTD] = acc[n][rr] + other[rr] + bv;
        }
    }
}

// ---------------------------------------------------------------------------
extern "C" void kernel_launch(void* const* d_in, const int* in_sizes, int n_in,
                              void* d_out, int out_size, void* d_ws, size_t ws_size,
                              hipStream_t stream) {
    const float* x     = (const float*)d_in[0];
    const float* adj   = (const float*)d_in[1];
    const float* nl_w  = (const float*)d_in[2];
    const float* nl_b  = (const float*)d_in[3];
    const float* w_out = (const float*)d_in[4];
    const float* b_out = (const float*)d_in[5];
    float* out = (float*)d_out;

    unsigned short* yt = (unsigned short*)d_ws;                       // 4 MB
    float* bias2 = (float*)((char*)d_ws + (size_t)NCOL * NODE * 2);   // 64 fp32

    bias2_kernel<<<1, 256, 0, stream>>>(nl_b, w_out, b_out, bias2);
    build_yt_kernel<<<512, 256, 0, stream>>>(x, nl_w, w_out, yt);
    gemm_adj_kernel<<<512, 512, 0, stream>>>(adj, yt, bias2, out);
}

// Round 4
// 477.040 us; speedup vs baseline: 1.2014x; 1.2014x over previous
//
#include <hip/hip_runtime.h>

#define NODE 8192
#define FEAT 64
#define OUTD 64
#define NCOL 256  // BATCH*OUTD

typedef float f32x4 __attribute__((ext_vector_type(4)));
typedef short s16x8 __attribute__((ext_vector_type(8)));
typedef short s16x4 __attribute__((ext_vector_type(4)));
typedef int   i32x4 __attribute__((ext_vector_type(4)));

__device__ __forceinline__ short f2bf(float f) {
    // round-to-nearest-even fp32 -> bf16 (finite inputs)
    unsigned u = __builtin_bit_cast(unsigned, f);
    u += 0x7FFFu + ((u >> 16) & 1u);
    return (short)(u >> 16);
}

__device__ __forceinline__ s16x4 cvt4(const f32x4& v) {
    s16x4 r;
#pragma unroll
    for (int i = 0; i < 4; ++i) r[i] = f2bf(v[i]);
    return r;
}

// ---------------------------------------------------------------------------
// k0: bias2[o] = b_out[o] + sum_f nl_b[f] * w_out[o,f]
// ---------------------------------------------------------------------------
__global__ void bias2_kernel(const float* __restrict__ nl_b,
                             const float* __restrict__ w_out,
                             const float* __restrict__ b_out,
                             float* __restrict__ bias2) {
    __shared__ float part[4][64];
    const int o = threadIdx.x & 63;
    const int fc = threadIdx.x >> 6;
    float s = 0.f;
#pragma unroll
    for (int i = 0; i < 16; ++i) {
        int f = fc * 16 + i;
        s += nl_b[f] * w_out[o * FEAT + f];
    }
    part[fc][o] = s;
    __syncthreads();
    if (fc == 0)
        bias2[o] = b_out[o] + part[0][o] + part[1][o] + part[2][o] + part[3][o];
}

// ---------------------------------------------------------------------------
// k0b: out[b,i,o] = bias2[o]  (gemm K-split accumulates via atomicAdd on top)
// 2M floats, f32x4 per thread.
// ---------------------------------------------------------------------------
__global__ __launch_bounds__(256) void init_out_kernel(
    float* __restrict__ out, const float* __restrict__ bias2) {
    const int idx = (int)blockIdx.x * 256 + threadIdx.x;
    f32x4 bv = *(const f32x4*)(bias2 + ((idx & 15) << 2));
    *(f32x4*)(out + (size_t)idx * 4) = bv;
}

// ---------------------------------------------------------------------------
// k1: Ybf = W2 @ x^T, written in MFMA B-FRAGMENT ORDER:
//   element (c, jn) at flat = (c16*256 + kb)*512 + (q*16 + (c&15))*8 + e
//   where c = b*64+o, c16=c>>4, kb=jn>>5, q=(jn>>3)&3, e=jn&7.
// So gemm's B-frag (c16, kb) load = base + lane*16B: one fully-coalesced
// global_load_dwordx4 (fixes the 16-line scatter of a [c][jn] layout).
// ---------------------------------------------------------------------------
__global__ __launch_bounds__(256) void build_ybf_kernel(
    const float* __restrict__ x, const float* __restrict__ nl_w,
    const float* __restrict__ w_out, unsigned short* __restrict__ ybf) {
    __shared__ float xs[64 * 65];
    __shared__ float w2s[64 * 65];
    const int tid = threadIdx.x;
    const int b   = (int)blockIdx.x >> 7;
    const int j0  = ((int)blockIdx.x & 127) << 6;

    const f32x4* src = (const f32x4*)(x + ((size_t)b * NODE + j0) * FEAT);
#pragma unroll
    for (int i = tid; i < 1024; i += 256) {
        f32x4 v = src[i];
        int j = i >> 4, f = (i & 15) << 2;
        float* d = &xs[j * 65 + f];
        d[0] = v[0]; d[1] = v[1]; d[2] = v[2]; d[3] = v[3];
    }
    for (int i = tid; i < 4096; i += 256) {
        int f = i & 63;
        w2s[(i >> 6) * 65 + f] = w_out[i] * (0.70710678118654752f * nl_w[f]);
    }
    __syncthreads();

    const int j  = tid & 63;
    const int o0 = (tid >> 6) << 4;
    float acc[16];
#pragma unroll
    for (int r = 0; r < 16; ++r) acc[r] = 0.f;
    for (int f = 0; f < 64; ++f) {
        float xv = xs[j * 65 + f];
#pragma unroll
        for (int r = 0; r < 16; ++r) acc[r] += w2s[(o0 + r) * 65 + f] * xv;
    }
    // swizzled store: c = b*64 + o0 + r  (o0 is 16-aligned -> c&15 == r)
    const int jn  = j0 + j;
    const int kb  = jn >> 5;
    const int q   = (jn >> 3) & 3;
    const int e   = jn & 7;
    const int c16 = b * 4 + (o0 >> 4);
    unsigned short* dst =
        ybf + ((size_t)(c16 * 256 + kb) * 512) + (size_t)q * 128 + e;
#pragma unroll
    for (int r = 0; r < 16; ++r) dst[r * 8] = (unsigned short)f2bf(acc[r]);
}

// ---------------------------------------------------------------------------
// k2: out += adj @ Y.  512 blocks x 256 thr; block = (rowgroup rg, colgroup
// cg=batch, K-half ks); wave wv of 4 owns rows row0=rg*128+wv*32 (32m x 64n
// x K=4096).  ***NO __syncthreads in the K-loop*** (R3 post-mortem: the
// barrier's vmcnt(0) drain let the compiler sink every prefetch load,
// VGPR=48, latency-serialized).  Each wave stages A through its PRIVATE LDS
// region; only waitcnts order it.  4-slot pipeline per round q:
//   load A(q+6) [global, 64B-coalesced] / cvt+LDS-write A(q+2) / frag-read
//   A(q) -> load->use distance 4 rounds (~1600cy > 900cy HBM).
// B: pre-swizzled Ybf, 1KB-contiguous dwordx4 per n-frag, depth-1 prefetch
// (L2-resident).  LDS row stride 40 elts: 16B-aligned, 8 lanes/4-bank span
// (optimal b128, no conflicts).  Epilogue: fp32 atomicAdd (out pre-init to
// bias2).
// ---------------------------------------------------------------------------
__global__ __launch_bounds__(256, 2) void gemm_adj_kernel(
    const float* __restrict__ adj, const unsigned short* __restrict__ ybf,
    float* __restrict__ out) {
    // per-wave: 4 bufs x 32 rows x 40 elts bf16 = 10KB; 4 waves = 40KB
    __shared__ __align__(16) unsigned short As[4][4][32 * 40];

    const int tid  = threadIdx.x;
    const int lane = tid & 63;
    const int wv   = tid >> 6;
    const int bi   = (int)blockIdx.x;
    const int rg   = bi >> 3;
    const int cg   = (bi >> 1) & 3;
    const int ks   = bi & 1;
    const int row0 = rg * 128 + wv * 32;
    const int t16  = lane & 15;
    const int quad = lane >> 4;
    const int sr   = lane >> 2;  // staging row within 16-group
    const int sc   = lane & 3;   // staging 16B chunk

    // A staging pointers: per inst (g,j): 16 rows x 64B fully coalesced
    const float* aGr[2];
    aGr[0] = adj + (size_t)(row0 + sr) * NODE + ks * 4096 + sc * 4;
    aGr[1] = aGr[0] + (size_t)16 * NODE;

    // B fragment pointers (swizzled Ybf): frag (nt, tile) = bpB[nt] + tile*512
    const unsigned short* bpB[4];
#pragma unroll
    for (int nt = 0; nt < 4; ++nt)
        bpB[nt] = ybf + ((size_t)((cg * 4 + nt) * 256 + ks * 128) * 512) + lane * 8;

    unsigned short* Aw = &As[wv][0][0];
    const int woff = sr * 40 + sc * 4;  // + g*640 + j*16

    f32x4 acc[2][4];
#pragma unroll
    for (int mi = 0; mi < 2; ++mi)
#pragma unroll
        for (int nt = 0; nt < 4; ++nt) acc[mi][nt] = (f32x4){0.f, 0.f, 0.f, 0.f};

    f32x4 aR[4][4];   // [slot][g*2+j]
    i32x4 BF[2][4];   // [phase][nt]

    // ---- prologue: fill pipeline ----
#pragma unroll
    for (int s = 0; s < 4; ++s)
#pragma unroll
        for (int g = 0; g < 2; ++g)
#pragma unroll
            for (int j = 0; j < 2; ++j)
                aR[s][g * 2 + j] = *(const f32x4*)(aGr[g] + s * 32 + j * 16);
#pragma unroll
    for (int nt = 0; nt < 4; ++nt) BF[0][nt] = *(const i32x4*)bpB[nt];
#pragma unroll
    for (int s = 0; s < 2; ++s) {
        unsigned short* wb = Aw + s * 1280;
#pragma unroll
        for (int g = 0; g < 2; ++g)
#pragma unroll
            for (int j = 0; j < 2; ++j)
                *(s16x4*)(wb + g * 640 + j * 16 + woff) = cvt4(aR[s][g * 2 + j]);
#pragma unroll
        for (int g = 0; g < 2; ++g)
#pragma unroll
            for (int j = 0; j < 2; ++j)
                aR[s][g * 2 + j] = *(const f32x4*)(aGr[g] + (4 + s) * 32 + j * 16);
    }

#define ROUND(qv, PH)                                                         \
    {                                                                         \
        /* B prefetch tile qv+1 */                                            \
        const int tB = (qv + 1) & 127;                                        \
        _Pragma("unroll") for (int nt = 0; nt < 4; ++nt)                      \
            BF[(PH + 1) & 1][nt] = *(const i32x4*)(bpB[nt] + (size_t)tB * 512); \
        /* cvt + LDS-write tile qv+2 (slot/buf (PH+2)&3) */                   \
        {                                                                     \
            unsigned short* wb = Aw + ((PH + 2) & 3) * 1280;                  \
            _Pragma("unroll") for (int g = 0; g < 2; ++g)                     \
                _Pragma("unroll") for (int j = 0; j < 2; ++j)                 \
                    *(s16x4*)(wb + g * 640 + j * 16 + woff) =                 \
                        cvt4(aR[(PH + 2) & 3][g * 2 + j]);                    \
        }                                                                     \
        /* A global load tile qv+6 into freed slot */                         \
        {                                                                     \
            const int ko = ((qv + 6) & 127) * 32;                             \
            _Pragma("unroll") for (int g = 0; g < 2; ++g)                     \
                _Pragma("unroll") for (int j = 0; j < 2; ++j)                 \
                    aR[(PH + 2) & 3][g * 2 + j] =                             \
                        *(const f32x4*)(aGr[g] + ko + j * 16);                \
        }                                                                     \
        /* frags + 8 MFMA */                                                  \
        {                                                                     \
            const unsigned short* rb = Aw + (PH & 3) * 1280;                  \
            s16x8 af0 = *(const s16x8*)(rb + t16 * 40 + quad * 8);            \
            s16x8 af1 = *(const s16x8*)(rb + (16 + t16) * 40 + quad * 8);     \
            _Pragma("unroll") for (int nt = 0; nt < 4; ++nt) {                \
                s16x8 bf = __builtin_bit_cast(s16x8, BF[PH & 1][nt]);         \
                acc[0][nt] = __builtin_amdgcn_mfma_f32_16x16x32_bf16(         \
                    af0, bf, acc[0][nt], 0, 0, 0);                            \
                acc[1][nt] = __builtin_amdgcn_mfma_f32_16x16x32_bf16(         \
                    af1, bf, acc[1][nt], 0, 0, 0);                            \
            }                                                                 \
        }                                                                     \
    }

#pragma unroll 1
    for (int q = 0; q < 128; q += 4) {
        ROUND(q + 0, 0)
        ROUND(q + 1, 1)
        ROUND(q + 2, 2)
        ROUND(q + 3, 3)
    }
#undef ROUND

    // ---- epilogue: accumulate into pre-biased out ----
#pragma unroll
    for (int mi = 0; mi < 2; ++mi) {
        const int i0 = row0 + mi * 16 + quad * 4;
#pragma unroll
        for (int nt = 0; nt < 4; ++nt) {
            float* op = out + ((size_t)cg * NODE + i0) * OUTD + nt * 16 + t16;
#pragma unroll
            for (int rr = 0; rr < 4; ++rr)
                atomicAdd(op + (size_t)rr * OUTD, acc[mi][nt][rr]);
        }
    }
}

// ---------------------------------------------------------------------------
extern "C" void kernel_launch(void* const* d_in, const int* in_sizes, int n_in,
                              void* d_out, int out_size, void* d_ws, size_t ws_size,
                              hipStream_t stream) {
    const float* x     = (const float*)d_in[0];
    const float* adj   = (const float*)d_in[1];
    const float* nl_w  = (const float*)d_in[2];
    const float* nl_b  = (const float*)d_in[3];
    const float* w_out = (const float*)d_in[4];
    const float* b_out = (const float*)d_in[5];
    float* out = (float*)d_out;

    unsigned short* ybf = (unsigned short*)d_ws;                      // 4 MB
    float* bias2 = (float*)((char*)d_ws + (size_t)NCOL * NODE * 2);   // 64 fp32

    bias2_kernel<<<1, 256, 0, stream>>>(nl_b, w_out, b_out, bias2);
    init_out_kernel<<<2048, 256, 0, stream>>>(out, bias2);
    build_ybf_kernel<<<512, 256, 0, stream>>>(x, nl_w, w_out, ybf);
    gemm_adj_kernel<<<512, 256, 0, stream>>>(adj, ybf, out);
}